// Round 1
// baseline (389.744 us; speedup 1.0000x reference)
//
#include <hip/hip_runtime.h>
#include <math.h>

#define SDE_B 16384
#define SDE_S 16
#define SDE_STEPS 50
#define SDE_L 128
#define SDE_DT 0.02f
#define SDE_SQRT_DT 0.14142135623730951f
#define SDE_TEMP 20.0f
#define LOG2E 1.44269504088896340736f
#define LN2 0.69314718055994530942f

#if __has_builtin(__builtin_amdgcn_exp2f)
__device__ __forceinline__ float fexp2(float x) { return __builtin_amdgcn_exp2f(x); }
#else
__device__ __forceinline__ float fexp2(float x) { return __exp2f(x); }
#endif

#if __has_builtin(__builtin_amdgcn_logf)
__device__ __forceinline__ float flog2(float x) { return __builtin_amdgcn_logf(x); }
#else
__device__ __forceinline__ float flog2(float x) { return __log2f(x); }
#endif

#if __has_builtin(__builtin_amdgcn_rcpf)
__device__ __forceinline__ float frcp(float x) { return __builtin_amdgcn_rcpf(x); }
#else
__device__ __forceinline__ float frcp(float x) { return 1.0f / x; }
#endif

// tanh(x) = 1 - 2/(e^{2x}+1), exact at +-inf saturation
__device__ __forceinline__ float tanh_fast(float x) {
    float e = fexp2(x * (2.0f * LOG2E));
    return fmaf(-2.0f, frcp(e + 1.0f), 1.0f);
}

// stable softplus: max(y,0) + log(1+exp(-|y|))
__device__ __forceinline__ float softplus_fast(float y) {
    float m = fmaxf(y, 0.0f);
    float e = fexp2(-fabsf(y) * LOG2E);
    return fmaf(LN2, flog2(1.0f + e), m);
}

__device__ __forceinline__ float sigmoid_fast(float y) {
    return frcp(1.0f + fexp2(-y * LOG2E));
}

// sum over the 4-lane quad (lanes grouped as sim*4+q) via DPP quad_perm
__device__ __forceinline__ float quad_sum(float v) {
#if __has_builtin(__builtin_amdgcn_mov_dpp)
    int i = __float_as_int(v);
    v += __int_as_float(__builtin_amdgcn_mov_dpp(i, 0xB1, 0xF, 0xF, true)); // xor 1
    i = __float_as_int(v);
    v += __int_as_float(__builtin_amdgcn_mov_dpp(i, 0x4E, 0xF, 0xF, true)); // xor 2
    return v;
#else
    v += __shfl_xor(v, 1, 64);
    v += __shfl_xor(v, 2, 64);
    return v;
#endif
}

__device__ __forceinline__ float fixnum(float v) {
    if (isnan(v)) return 0.0f;
    if (isinf(v)) return v > 0.0f ? 3.4028234663852886e38f : -3.4028234663852886e38f;
    return v;
}

// One wave per batch element b. 64 lanes = 16 sims x 4 hidden-quarters.
// lane = s*4 + q: lane handles sim s, hidden units j in [16q, 16q+16).
// Weights + zW1 slice live in VGPRs for the whole 50-step loop.
__global__ void __launch_bounds__(256) sde_kernel(
    const float* __restrict__ z,  const float* __restrict__ W1,
    const float* __restrict__ b1, const float* __restrict__ W2,
    const float* __restrict__ b2, const float* __restrict__ Wb,
    const float* __restrict__ bb, const float* __restrict__ Wn,
    const float* __restrict__ bn, const float* __restrict__ osc,
    const float* __restrict__ obias, const float* __restrict__ noise,
    float* __restrict__ out)
{
    __shared__ float w1s[64 * 130];
    for (int i = threadIdx.x; i < 64 * 130; i += 256) w1s[i] = W1[i];
    __syncthreads();

    const int lane = threadIdx.x & 63;
    const int wv = threadIdx.x >> 6;
    const int b = blockIdx.x * 4 + wv;
    if (b >= SDE_B) return;
    const int s = lane >> 2;
    const int q = lane & 3;

    const float* zr = z + (size_t)b * SDE_L;

    // --- setup: lane `l` computes zW1 entry for hidden unit j = l ---
    float accz = b1[lane];
    #pragma unroll
    for (int m = 0; m < SDE_L; m += 4) {
        float z0 = zr[m], z1 = zr[m + 1], z2 = zr[m + 2], z3 = zr[m + 3];
        const float* wrow = &w1s[lane * 130 + 2 + m];
        accz = fmaf(z0, wrow[0], accz);
        accz = fmaf(z1, wrow[1], accz);
        accz = fmaf(z2, wrow[2], accz);
        accz = fmaf(z3, wrow[3], accz);
    }

    // --- boundary / ndt: 128-dot reduced over the wave ---
    float zb0 = zr[2 * lane], zb1 = zr[2 * lane + 1];
    float pb = fmaf(zb0, Wb[2 * lane], zb1 * Wb[2 * lane + 1]);
    float pn = fmaf(zb0, Wn[2 * lane], zb1 * Wn[2 * lane + 1]);
    #pragma unroll
    for (int off = 32; off > 0; off >>= 1) {
        pb += __shfl_xor(pb, off, 64);
        pn += __shfl_xor(pn, off, 64);
    }
    const float half_b = 0.5f * (softplus_fast(pb + bb[0]) + 0.3f);
    const float ndt = softplus_fast(pn + bn[0]) + 0.05f;

    // --- redistribute zW1 + load this lane's 16 hidden units' weights ---
    float zw[16], w1x[16], w1t[16], w2a[16], w2b[16];
    #pragma unroll
    for (int i = 0; i < 16; ++i) {
        int j = q * 16 + i;
        zw[i]  = __shfl(accz, j, 64);
        w1x[i] = w1s[j * 130 + 0];
        w1t[i] = w1s[j * 130 + 1];
        w2a[i] = W2[j];
        w2b[i] = W2[64 + j];
    }

    const float b20 = b2[0], b21 = b2[1];
    const float* nzp = noise + (size_t)b * SDE_S + s;

    float x = 0.0f, ls = 0.0f, ert = 0.0f, ecorr = 0.0f;

    for (int k = 0; k < SDE_STEPS; ++k) {
        float nz = nzp[(size_t)k * (SDE_B * SDE_S)];
        float t = (float)k * SDE_DT;
        float a0 = 0.0f, a1 = 0.0f;
        #pragma unroll
        for (int i = 0; i < 16; ++i) {
            float pre = fmaf(x, w1x[i], fmaf(t, w1t[i], zw[i]));
            float h = tanh_fast(pre);
            a0 = fmaf(h, w2a[i], a0);
            a1 = fmaf(h, w2b[i], a1);
        }
        a0 = quad_sum(a0);
        a1 = quad_sum(a1);
        // identical on all 4 lanes of the quad -> state stays consistent
        float drift = fminf(fmaxf(a0 + b20, -5.0f), 5.0f);
        float diff = softplus_fast(a1 + b21) + 0.1f;
        x = fmaf(drift, SDE_DT, fmaf(diff * SDE_SQRT_DT, nz, x));
        x = fminf(fmaxf(x, -10.0f), 10.0f);
        float dist = fabsf(x) - half_b;
        float hz = fminf(sigmoid_fast(SDE_TEMP * dist), 0.99f);
        float surv = fexp2(fmaxf(ls, -50.0f) * LOG2E);
        float cross = surv * hz;
        ls += LN2 * flog2(1.0f - hz);
        float tn = (float)(k + 1) * SDE_DT;
        ert = fmaf(cross, tn, ert);
        ecorr += (x > 0.0f) ? cross : 0.0f;
    }

    float rem = fexp2(fmaxf(ls, -50.0f) * LOG2E);
    ert += rem;                    // * (STEPS*DT) = 1.0
    ecorr = fmaf(rem, 0.5f, ecorr);
    float rt = ert + ndt;          // seconds; x1000 applied after stats

    // --- stats over 16 sims (mask quad-redundant copies to q==0) ---
    float sr = (q == 0) ? rt : 0.0f;
    float scr = (q == 0) ? ecorr : 0.0f;
    #pragma unroll
    for (int off = 32; off > 0; off >>= 1) {
        sr += __shfl_xor(sr, off, 64);
        scr += __shfl_xor(scr, off, 64);
    }
    float mean = sr * (1.0f / 16.0f);
    float d = rt - mean;
    float vv = (q == 0) ? d * d : 0.0f;
    #pragma unroll
    for (int off = 32; off > 0; off >>= 1) vv += __shfl_xor(vv, off, 64);

    if (lane == 0) {
        float std_ms = sqrtf(vv * (1.0f / 15.0f)) * 1000.0f + 0.001f;
        float o0 = fmaf(mean * 1000.0f, osc[0], obias[0]);
        float o1 = fmaf(std_ms, osc[1], obias[1]);
        float o2 = fmaf(scr * (1.0f / 16.0f), osc[2], obias[2]);
        out[b * 3 + 0] = fixnum(o0);
        out[b * 3 + 1] = fixnum(o1);
        out[b * 3 + 2] = fixnum(o2);
    }
}

extern "C" void kernel_launch(void* const* d_in, const int* in_sizes, int n_in,
                              void* d_out, int out_size, void* d_ws, size_t ws_size,
                              hipStream_t stream) {
    const float* z     = (const float*)d_in[0];
    const float* W1    = (const float*)d_in[1];
    const float* b1    = (const float*)d_in[2];
    const float* W2    = (const float*)d_in[3];
    const float* b2    = (const float*)d_in[4];
    const float* Wb    = (const float*)d_in[5];
    const float* bb    = (const float*)d_in[6];
    const float* Wn    = (const float*)d_in[7];
    const float* bn    = (const float*)d_in[8];
    const float* osc   = (const float*)d_in[9];
    const float* obias = (const float*)d_in[10];
    const float* noise = (const float*)d_in[11];
    float* out = (float*)d_out;

    dim3 grid(SDE_B / 4), block(256);
    sde_kernel<<<grid, block, 0, stream>>>(z, W1, b1, W2, b2, Wb, bb, Wn, bn,
                                           osc, obias, noise, out);
}